// Round 8
// baseline (977.460 us; speedup 1.0000x reference)
//
#include <hip/hip_runtime.h>
#include <hip/hip_bf16.h>

#define N_NODES 100000
#define N_EDGES 300000
#define CH 256
#define EPS 1e-5f

typedef __hip_bfloat16 bf16;
typedef __attribute__((ext_vector_type(8))) short bf16x8_t;  // 8 bf16 (4 VGPRs)
typedef __attribute__((ext_vector_type(4))) float f32x4_t;   // 4 fp32 acc

__device__ __forceinline__ unsigned short f2bf(float f) {
    bf16 h = __float2bfloat16(f);
    return __builtin_bit_cast(unsigned short, h);
}
__device__ __forceinline__ float bf2f(unsigned short u) {
    unsigned int x = ((unsigned int)u) << 16;  // exact widening
    return __builtin_bit_cast(float, x);
}
__device__ __forceinline__ float bflo(unsigned int w) {
    return __builtin_bit_cast(float, w << 16);
}
__device__ __forceinline__ float bfhi(unsigned int w) {
    return __builtin_bit_cast(float, w & 0xffff0000u);
}
__device__ __forceinline__ void store4(float* p, float4 v) { *(float4*)p = v; }
__device__ __forceinline__ void store4(bf16* p, float4 v) {
    ushort4 o; o.x = f2bf(v.x); o.y = f2bf(v.y); o.z = f2bf(v.z); o.w = f2bf(v.w);
    *(ushort4*)p = o;
}
__device__ __forceinline__ void store_val(float* p, float v) { *p = v; }
__device__ __forceinline__ void store_val(bf16* p, float v) { *p = __float2bfloat16(v); }

__device__ __forceinline__ void async_copy16(const void* g, void* l) {
    __builtin_amdgcn_global_load_lds((const __attribute__((address_space(1))) void*)g,
                                     (__attribute__((address_space(3))) void*)l, 16, 0, 0);
}

// ================= CSR build =================
__global__ void k_zero_int(int* __restrict__ p, int n) {
    int i = blockIdx.x * 256 + threadIdx.x;
    if (i < n) p[i] = 0;
}
__global__ void k_count_deg(const int* __restrict__ dst, int* __restrict__ deg) {
    int e = blockIdx.x * 256 + threadIdx.x;
    if (e < N_EDGES) atomicAdd(&deg[dst[e]], 1);
}
__global__ void k_dinv_from_deg(const int* __restrict__ deg, float* __restrict__ dinv) {
    int i = blockIdx.x * 256 + threadIdx.x;
    if (i < N_NODES) dinv[i] = rsqrtf((float)(deg[i] + 1));  // +1 self loop
}
__global__ void k_block_sums(const int* __restrict__ deg, int* __restrict__ bsum) {
    __shared__ int s[256];
    int t = threadIdx.x;
    int i = blockIdx.x * 256 + t;
    s[t] = (i < N_NODES) ? deg[i] : 0;
    __syncthreads();
    for (int off = 128; off > 0; off >>= 1) {
        if (t < off) s[t] += s[t + off];
        __syncthreads();
    }
    if (t == 0) bsum[blockIdx.x] = s[0];
}
__global__ void k_scan_bsums(int* __restrict__ bsum, int nb) {
    __shared__ int s[512];
    int t = threadIdx.x;
    int v = (t < nb) ? bsum[t] : 0;
    s[t] = v;
    __syncthreads();
    for (int off = 1; off < 512; off <<= 1) {
        int u = (t >= off) ? s[t - off] : 0;
        __syncthreads();
        s[t] += u;
        __syncthreads();
    }
    if (t < nb) bsum[t] = s[t] - v;  // exclusive
}
__global__ void k_row_ptr(const int* __restrict__ deg, const int* __restrict__ bsum,
                          int* __restrict__ row_ptr) {
    __shared__ int s[256];
    int t = threadIdx.x;
    int i = blockIdx.x * 256 + t;
    int v = (i < N_NODES) ? deg[i] : 0;
    s[t] = v;
    __syncthreads();
    for (int off = 1; off < 256; off <<= 1) {
        int u = (t >= off) ? s[t - off] : 0;
        __syncthreads();
        s[t] += u;
        __syncthreads();
    }
    if (i < N_NODES) row_ptr[i] = bsum[blockIdx.x] + s[t] - v;  // exclusive
    if (blockIdx.x == 0 && t == 0) row_ptr[N_NODES] = N_EDGES;
}
__global__ void k_scatter(const int* __restrict__ src, const int* __restrict__ dst,
                          const int* __restrict__ row_ptr, int* __restrict__ cursor,
                          int* __restrict__ col) {
    int e = blockIdx.x * 256 + threadIdx.x;
    if (e < N_EDGES) {
        int d = dst[e];
        int p = atomicAdd(&cursor[d], 1);
        col[row_ptr[d] + p] = src[e];
    }
}

// ================= all weight transposes in one kernel =================
// wt[which][n][k] = W_which[row_off+k][n], 5 matrices of 256x256
__global__ void k_transpose_all(const float* __restrict__ W1, const float* __restrict__ W2,
                                const float* __restrict__ W3, const float* __restrict__ fc1w,
                                bf16* __restrict__ wt) {
    int which = blockIdx.x >> 8;  // 0..4
    int idx = ((blockIdx.x & 255) << 8) + threadIdx.x;
    int n = idx >> 8, k = idx & 255;
    const float* W; int ro = 0;
    switch (which) {
        case 0: W = W1; break;
        case 1: W = W2; break;
        case 2: W = W3; break;
        case 3: W = fc1w; break;
        default: W = fc1w; ro = 256; break;
    }
    wt[(size_t)which * 65536 + (size_t)n * 256 + k] =
        __float2bfloat16(W[(size_t)(ro + k) * 256 + n]);
}

// ================= casts =================
__global__ void k_cast_bf16_v4(const float* __restrict__ x, unsigned short* __restrict__ y) {
    int i = blockIdx.x * 256 + threadIdx.x;  // over NF/4
    float4 v = ((const float4*)x)[i];
    ushort4 o;
    o.x = f2bf(v.x); o.y = f2bf(v.y); o.z = f2bf(v.z); o.w = f2bf(v.w);
    ((ushort4*)y)[i] = o;
}
// in-place BN apply + relu on bf16 buffer
__global__ void k_bn_relu_bf16(unsigned short* __restrict__ x, const float* __restrict__ scale,
                               const float* __restrict__ shift) {
    int i = blockIdx.x * 256 + threadIdx.x;  // over NF/4
    ushort4 m = ((ushort4*)x)[i];
    int c = (i & 63) * 4;
    float4 sc = *(const float4*)(scale + c);
    float4 sh = *(const float4*)(shift + c);
    ushort4 o;
    o.x = f2bf(fmaxf(bf2f(m.x) * sc.x + sh.x, 0.f));
    o.y = f2bf(fmaxf(bf2f(m.y) * sc.y + sh.y, 0.f));
    o.z = f2bf(fmaxf(bf2f(m.z) * sc.z + sh.z, 0.f));
    o.w = f2bf(fmaxf(bf2f(m.w) * sc.w + sh.w, 0.f));
    ((ushort4*)x)[i] = o;
}

// ================= bf16 MFMA GEMM: C[M x N] = A[M x 256] @ Bt[N x 256]^T =================
// 128x128 tile, BK=64, 4 waves (2x2), each wave 64x64 via 4x4 of 16x16x32 MFMA.
// ldc = C row stride (N). gridDim.x = N/128.
template <typename OutT>
__global__ __launch_bounds__(256) void k_gemm_mfma(const bf16* __restrict__ A,
                                                   const bf16* __restrict__ Bt,
                                                   OutT* __restrict__ C, int M, int ldc) {
    __shared__ bf16 As[128 * 64];
    __shared__ bf16 Bs[128 * 64];
    const int tid = threadIdx.x;
    const int lane = tid & 63;
    const int w = tid >> 6;
    const int wr = w >> 1, wc = w & 1;
    const int lr = lane & 15, quad = lane >> 4;
    const int row0 = blockIdx.y * 128;
    const int col0 = blockIdx.x * 128;

    f32x4_t acc[4][4] = {};

    for (int k0 = 0; k0 < 256; k0 += 64) {
#pragma unroll
        for (int i = 0; i < 4; ++i) {
            int j = i * 256 + tid;
            int r = j >> 3, c = j & 7;
            int gk = ((c ^ (r & 7)) << 3);
            int gr = row0 + r; gr = gr < M ? gr : M - 1;
            async_copy16(A + (size_t)gr * 256 + k0 + gk, (void*)(As + j * 8));
            async_copy16(Bt + (size_t)(col0 + r) * 256 + k0 + gk, (void*)(Bs + j * 8));
        }
        __syncthreads();
#pragma unroll
        for (int ks = 0; ks < 2; ++ks) {
            bf16x8_t af[4], bfr[4];
#pragma unroll
            for (int mi = 0; mi < 4; ++mi) {
                int m = wr * 64 + mi * 16 + lr;
                int c = (ks * 4 + quad) ^ (m & 7);
                af[mi] = *(const bf16x8_t*)(As + m * 64 + c * 8);
            }
#pragma unroll
            for (int ni = 0; ni < 4; ++ni) {
                int n = wc * 64 + ni * 16 + lr;
                int c = (ks * 4 + quad) ^ (n & 7);
                bfr[ni] = *(const bf16x8_t*)(Bs + n * 64 + c * 8);
            }
#pragma unroll
            for (int mi = 0; mi < 4; ++mi)
#pragma unroll
                for (int ni = 0; ni < 4; ++ni)
                    acc[mi][ni] = __builtin_amdgcn_mfma_f32_16x16x32_bf16(
                        af[mi], bfr[ni], acc[mi][ni], 0, 0, 0);
        }
        __syncthreads();
    }
    // epilogue: C/D layout col=lane&15, row=quad*4+reg
#pragma unroll
    for (int mi = 0; mi < 4; ++mi) {
#pragma unroll
        for (int r = 0; r < 4; ++r) {
            int row = row0 + wr * 64 + mi * 16 + quad * 4 + r;
            if (row < M) {
#pragma unroll
                for (int ni = 0; ni < 4; ++ni) {
                    int colg = col0 + wc * 64 + ni * 16 + lr;
                    store_val(C + (size_t)row * ldc + colg, acc[mi][ni][r]);
                }
            }
        }
    }
}

// ================= CSR aggregation (bf16 xw in, bf16 out, no atomics) =================
__global__ void k_agg_csr(const unsigned short* __restrict__ xw, const float* __restrict__ dinv,
                          const int* __restrict__ row_ptr, const int* __restrict__ col,
                          const float* __restrict__ bias, bf16* __restrict__ out) {
    int wave = threadIdx.x >> 6, lane = threadIdx.x & 63;
    int node = blockIdx.x * 4 + wave;
    if (node >= N_NODES) return;
    int beg = row_ptr[node], end = row_ptr[node + 1];
    float dv = dinv[node];
    const ushort4* xwv = (const ushort4*)xw;
    ushort4 xr = xwv[(size_t)node * 64 + lane];
    float s2 = dv * dv;
    float4 acc;
    acc.x = s2 * bf2f(xr.x); acc.y = s2 * bf2f(xr.y);
    acc.z = s2 * bf2f(xr.z); acc.w = s2 * bf2f(xr.w);
    for (int i = beg; i < end; ++i) {
        int s = col[i];
        float wgt = dv * dinv[s];
        ushort4 m = xwv[(size_t)s * 64 + lane];
        acc.x += wgt * bf2f(m.x); acc.y += wgt * bf2f(m.y);
        acc.z += wgt * bf2f(m.z); acc.w += wgt * bf2f(m.w);
    }
    float4 bv = ((const float4*)bias)[lane];
    acc.x += bv.x; acc.y += bv.y; acc.z += bv.z; acc.w += bv.w;
    store4(out + (size_t)node * CH + lane * 4, acc);
}

// ================= batch norm stats: bf16 input, 64 rows/block, LDS reduce ==========
__global__ void k_bn_zero(float* bnsum, float* bnsumsq) {
    int c = threadIdx.x;
    bnsum[c] = 0.f; bnsumsq[c] = 0.f;
}
__global__ __launch_bounds__(256) void k_bn_stats(const unsigned short* __restrict__ x,
                                                  float* __restrict__ bnsum,
                                                  float* __restrict__ bnsumsq) {
    __shared__ float sred[4][64][4];
    __shared__ float qred[4][64][4];
    int t = threadIdx.x;
    int cg = t & 63, rg = t >> 6;  // 64 channel-groups x 4 row-groups
    int r0 = blockIdx.x * 64;
    float s0 = 0, s1 = 0, s2 = 0, s3 = 0, q0 = 0, q1 = 0, q2 = 0, q3 = 0;
#pragma unroll
    for (int i = 0; i < 16; ++i) {
        int r = r0 + rg + 4 * i;
        if (r < N_NODES) {
            ushort4 m = ((const ushort4*)(x + (size_t)r * 256))[cg];
            float v0 = bf2f(m.x), v1 = bf2f(m.y), v2 = bf2f(m.z), v3 = bf2f(m.w);
            s0 += v0; s1 += v1; s2 += v2; s3 += v3;
            q0 += v0 * v0; q1 += v1 * v1; q2 += v2 * v2; q3 += v3 * v3;
        }
    }
    sred[rg][cg][0] = s0; sred[rg][cg][1] = s1; sred[rg][cg][2] = s2; sred[rg][cg][3] = s3;
    qred[rg][cg][0] = q0; qred[rg][cg][1] = q1; qred[rg][cg][2] = q2; qred[rg][cg][3] = q3;
    __syncthreads();
    if (rg == 0) {
#pragma unroll
        for (int g = 1; g < 4; ++g) {
            s0 += sred[g][cg][0]; s1 += sred[g][cg][1];
            s2 += sred[g][cg][2]; s3 += sred[g][cg][3];
            q0 += qred[g][cg][0]; q1 += qred[g][cg][1];
            q2 += qred[g][cg][2]; q3 += qred[g][cg][3];
        }
        atomicAdd(&bnsum[cg * 4 + 0], s0); atomicAdd(&bnsum[cg * 4 + 1], s1);
        atomicAdd(&bnsum[cg * 4 + 2], s2); atomicAdd(&bnsum[cg * 4 + 3], s3);
        atomicAdd(&bnsumsq[cg * 4 + 0], q0); atomicAdd(&bnsumsq[cg * 4 + 1], q1);
        atomicAdd(&bnsumsq[cg * 4 + 2], q2); atomicAdd(&bnsumsq[cg * 4 + 3], q3);
    }
}
__global__ void k_bn_finalize(const float* __restrict__ bnsum, const float* __restrict__ bnsumsq,
                              const float* __restrict__ g, const float* __restrict__ be,
                              float* scale, float* shift) {
    int c = threadIdx.x;
    float mu = bnsum[c] * (1.0f / N_NODES);
    float var = bnsumsq[c] * (1.0f / N_NODES) - mu * mu;
    float sc = g[c] * rsqrtf(var + EPS);
    scale[c] = sc;
    shift[c] = be[c] - mu * sc;
}

// ================= edge scoring: 2 edges/wave, 32 lanes each, 8 ch/lane =================
// uv layout: [node][512] bf16, u = cols 0..255, v = cols 256..511
__global__ __launch_bounds__(256) void k_edge_score(
        const unsigned short* __restrict__ uv,
        const int* __restrict__ src, const int* __restrict__ dst,
        const int* __restrict__ neg, const float* __restrict__ fc1_b,
        const float* __restrict__ fc2_w, const float* __restrict__ fc2_b,
        float* __restrict__ out) {
    int wave = threadIdx.x >> 6, lane = threadIdx.x & 63;
    int half = lane >> 5, l = lane & 31;
    int e = blockIdx.x * 8 + wave * 2 + half;
    if (e >= N_EDGES) return;
    int s = src[e], d = dst[e], g = neg[e];
    uint4 uu = ((const uint4*)(uv + (size_t)s * 512))[l];
    uint4 vp = ((const uint4*)(uv + (size_t)d * 512 + 256))[l];
    uint4 vn = ((const uint4*)(uv + (size_t)g * 512 + 256))[l];
    float4 b0 = ((const float4*)fc1_b)[l * 2];
    float4 b1 = ((const float4*)fc1_b)[l * 2 + 1];
    float4 w0 = ((const float4*)fc2_w)[l * 2];
    float4 w1 = ((const float4*)fc2_w)[l * 2 + 1];

    float t0 = bflo(uu.x) + b0.x, t1 = bfhi(uu.x) + b0.y;
    float t2 = bflo(uu.y) + b0.z, t3 = bfhi(uu.y) + b0.w;
    float t4 = bflo(uu.z) + b1.x, t5 = bfhi(uu.z) + b1.y;
    float t6 = bflo(uu.w) + b1.z, t7 = bfhi(uu.w) + b1.w;

    float accp = fmaxf(t0 + bflo(vp.x), 0.f) * w0.x + fmaxf(t1 + bfhi(vp.x), 0.f) * w0.y +
                 fmaxf(t2 + bflo(vp.y), 0.f) * w0.z + fmaxf(t3 + bfhi(vp.y), 0.f) * w0.w +
                 fmaxf(t4 + bflo(vp.z), 0.f) * w1.x + fmaxf(t5 + bfhi(vp.z), 0.f) * w1.y +
                 fmaxf(t6 + bflo(vp.w), 0.f) * w1.z + fmaxf(t7 + bfhi(vp.w), 0.f) * w1.w;
    float accn = fmaxf(t0 + bflo(vn.x), 0.f) * w0.x + fmaxf(t1 + bfhi(vn.x), 0.f) * w0.y +
                 fmaxf(t2 + bflo(vn.y), 0.f) * w0.z + fmaxf(t3 + bfhi(vn.y), 0.f) * w0.w +
                 fmaxf(t4 + bflo(vn.z), 0.f) * w1.x + fmaxf(t5 + bfhi(vn.z), 0.f) * w1.y +
                 fmaxf(t6 + bflo(vn.w), 0.f) * w1.z + fmaxf(t7 + bfhi(vn.w), 0.f) * w1.w;
#pragma unroll
    for (int off = 16; off > 0; off >>= 1) {
        accp += __shfl_down(accp, off, 64);
        accn += __shfl_down(accn, off, 64);
    }
    if (l == 0) {
        float bb = fc2_b[0];
        out[e] = 1.0f / (1.0f + expf(-(accp + bb)));
        out[N_EDGES + e] = 1.0f / (1.0f + expf(-(accn + bb)));
    }
}

extern "C" void kernel_launch(void* const* d_in, const int* in_sizes, int n_in,
                              void* d_out, int out_size, void* d_ws, size_t ws_size,
                              hipStream_t stream) {
    const float* node_feat = (const float*)d_in[0];
    const int* src = (const int*)d_in[1];
    const int* dst = (const int*)d_in[2];
    const int* neg = (const int*)d_in[3];
    const float* W1 = (const float*)d_in[4];  const float* b1 = (const float*)d_in[5];
    const float* W2 = (const float*)d_in[6];  const float* b2 = (const float*)d_in[7];
    const float* W3 = (const float*)d_in[8];  const float* b3 = (const float*)d_in[9];
    const float* g1 = (const float*)d_in[10]; const float* be1 = (const float*)d_in[11];
    const float* g2 = (const float*)d_in[12]; const float* be2 = (const float*)d_in[13];
    const float* fc1_w = (const float*)d_in[14]; const float* fc1_b = (const float*)d_in[15];
    const float* fc2_w = (const float*)d_in[16]; const float* fc2_b = (const float*)d_in[17];
    float* out = (float*)d_out;

    // ---- workspace layout (~208 MB total, all-bf16 activations) ----
    const size_t NF = (size_t)N_NODES * CH;  // 25,600,000
    bf16* UV = (bf16*)d_ws;                  // [node][512] u|v (2*NF)
    bf16* Xbf = UV + 2 * NF;                 // bf16 activations / agg out / z (NF)
    bf16* XwBf = Xbf + NF;                   // bf16 GEMM output xw (NF)
    bf16* wt = XwBf + NF;                    // 5 * 65536 (wt1,wt2,wt3,wtu,wtv)
    float* dinv = (float*)(wt + 5 * 65536);
    float* bnsum = dinv + N_NODES;           // 256
    float* bnsumsq = bnsum + CH;             // 256
    float* scale = bnsumsq + CH;
    float* shift = scale + CH;
    int* ideg = (int*)(shift + CH);          // N (cursor follows: zeroed together)
    int* cursor = ideg + N_NODES;
    int* row_ptr = cursor + N_NODES;
    int* col = row_ptr + N_NODES + 1;
    int* bsum = col + N_EDGES;               // 512
    (void)ws_size;

    dim3 gemmGrid(2, (N_NODES + 127) / 128);   // 2 x 782
    dim3 uvGrid(4, (N_NODES + 127) / 128);     // 4 x 782 (N=512)
    int nodeBlocks = (N_NODES + 255) / 256;    // 391
    int edgeBlocks = (N_EDGES + 255) / 256;
    int aggBlocks = (N_NODES + 3) / 4;
    int bnBlocks = (N_NODES + 63) / 64;        // 1563
    int v4Blocks = (int)(NF / 4 / 256);        // 25000
    int scoreBlocks = (N_EDGES + 7) / 8;       // 37500

    // ---- CSR build + dinv ----
    k_zero_int<<<(2 * N_NODES + 255) / 256, 256, 0, stream>>>(ideg, 2 * N_NODES);
    k_count_deg<<<edgeBlocks, 256, 0, stream>>>(dst, ideg);
    k_dinv_from_deg<<<nodeBlocks, 256, 0, stream>>>(ideg, dinv);
    k_block_sums<<<nodeBlocks, 256, 0, stream>>>(ideg, bsum);
    k_scan_bsums<<<1, 512, 0, stream>>>(bsum, nodeBlocks);
    k_row_ptr<<<nodeBlocks, 256, 0, stream>>>(ideg, bsum, row_ptr);
    k_scatter<<<edgeBlocks, 256, 0, stream>>>(src, dst, row_ptr, cursor, col);

    // ---- all weight transposes ----
    k_transpose_all<<<1280, 256, 0, stream>>>(W1, W2, W3, fc1_w, wt);

    // ---- layer 1 ----
    k_cast_bf16_v4<<<v4Blocks, 256, 0, stream>>>(node_feat, (unsigned short*)Xbf);
    k_gemm_mfma<bf16><<<gemmGrid, 256, 0, stream>>>(Xbf, wt, XwBf, N_NODES, 256);
    k_agg_csr<<<aggBlocks, 256, 0, stream>>>((unsigned short*)XwBf, dinv, row_ptr, col, b1, Xbf);
    k_bn_zero<<<1, 256, 0, stream>>>(bnsum, bnsumsq);
    k_bn_stats<<<bnBlocks, 256, 0, stream>>>((unsigned short*)Xbf, bnsum, bnsumsq);
    k_bn_finalize<<<1, 256, 0, stream>>>(bnsum, bnsumsq, g1, be1, scale, shift);
    k_bn_relu_bf16<<<v4Blocks, 256, 0, stream>>>((unsigned short*)Xbf, scale, shift);

    // ---- layer 2 ----
    k_gemm_mfma<bf16><<<gemmGrid, 256, 0, stream>>>(Xbf, wt + 65536, XwBf, N_NODES, 256);
    k_agg_csr<<<aggBlocks, 256, 0, stream>>>((unsigned short*)XwBf, dinv, row_ptr, col, b2, Xbf);
    k_bn_zero<<<1, 256, 0, stream>>>(bnsum, bnsumsq);
    k_bn_stats<<<bnBlocks, 256, 0, stream>>>((unsigned short*)Xbf, bnsum, bnsumsq);
    k_bn_finalize<<<1, 256, 0, stream>>>(bnsum, bnsumsq, g2, be2, scale, shift);
    k_bn_relu_bf16<<<v4Blocks, 256, 0, stream>>>((unsigned short*)Xbf, scale, shift);

    // ---- layer 3: agg writes z (bf16) into Xbf ----
    k_gemm_mfma<bf16><<<gemmGrid, 256, 0, stream>>>(Xbf, wt + 2 * 65536, XwBf, N_NODES, 256);
    k_agg_csr<<<aggBlocks, 256, 0, stream>>>((unsigned short*)XwBf, dinv, row_ptr, col, b3, Xbf);

    // ---- link predictor: UV = z @ [wtu|wtv]^T (single N=512 GEMM) ----
    k_gemm_mfma<bf16><<<uvGrid, 256, 0, stream>>>(Xbf, wt + 3 * 65536, UV, N_NODES, 512);
    k_edge_score<<<scoreBlocks, 256, 0, stream>>>((unsigned short*)UV, src, dst, neg,
                                                  fc1_b, fc2_w, fc2_b, out);
}

// Round 9
// 703.179 us; speedup vs baseline: 1.3901x; 1.3901x over previous
//
#include <hip/hip_runtime.h>
#include <hip/hip_bf16.h>

#define N_NODES 100000
#define N_EDGES 300000
#define CH 256
#define EPS 1e-5f
#define BN_BLOCKS 1563  // ceil(N_NODES/64)

typedef __hip_bfloat16 bf16;
typedef __attribute__((ext_vector_type(8))) short bf16x8_t;  // 8 bf16 (4 VGPRs)
typedef __attribute__((ext_vector_type(4))) float f32x4_t;   // 4 fp32 acc

__device__ __forceinline__ unsigned short f2bf(float f) {
    bf16 h = __float2bfloat16(f);
    return __builtin_bit_cast(unsigned short, h);
}
__device__ __forceinline__ float bf2f(unsigned short u) {
    unsigned int x = ((unsigned int)u) << 16;  // exact widening
    return __builtin_bit_cast(float, x);
}
__device__ __forceinline__ float bflo(unsigned int w) {
    return __builtin_bit_cast(float, w << 16);
}
__device__ __forceinline__ float bfhi(unsigned int w) {
    return __builtin_bit_cast(float, w & 0xffff0000u);
}
__device__ __forceinline__ void store4(float* p, float4 v) { *(float4*)p = v; }
__device__ __forceinline__ void store4(bf16* p, float4 v) {
    ushort4 o; o.x = f2bf(v.x); o.y = f2bf(v.y); o.z = f2bf(v.z); o.w = f2bf(v.w);
    *(ushort4*)p = o;
}
__device__ __forceinline__ void store_val(float* p, float v) { *p = v; }
__device__ __forceinline__ void store_val(bf16* p, float v) { *p = __float2bfloat16(v); }

__device__ __forceinline__ void async_copy16(const void* g, void* l) {
    __builtin_amdgcn_global_load_lds((const __attribute__((address_space(1))) void*)g,
                                     (__attribute__((address_space(3))) void*)l, 16, 0, 0);
}

// ================= CSR build =================
__global__ void k_zero_int(int* __restrict__ p, int n) {
    int i = blockIdx.x * 256 + threadIdx.x;
    if (i < n) p[i] = 0;
}
__global__ void k_count_deg(const int* __restrict__ dst, int* __restrict__ deg) {
    int e = blockIdx.x * 256 + threadIdx.x;
    if (e < N_EDGES) atomicAdd(&deg[dst[e]], 1);
}
__global__ void k_dinv_from_deg(const int* __restrict__ deg, float* __restrict__ dinv) {
    int i = blockIdx.x * 256 + threadIdx.x;
    if (i < N_NODES) dinv[i] = rsqrtf((float)(deg[i] + 1));  // +1 self loop
}
__global__ void k_block_sums(const int* __restrict__ deg, int* __restrict__ bsum) {
    __shared__ int s[256];
    int t = threadIdx.x;
    int i = blockIdx.x * 256 + t;
    s[t] = (i < N_NODES) ? deg[i] : 0;
    __syncthreads();
    for (int off = 128; off > 0; off >>= 1) {
        if (t < off) s[t] += s[t + off];
        __syncthreads();
    }
    if (t == 0) bsum[blockIdx.x] = s[0];
}
__global__ void k_scan_bsums(int* __restrict__ bsum, int nb) {
    __shared__ int s[512];
    int t = threadIdx.x;
    int v = (t < nb) ? bsum[t] : 0;
    s[t] = v;
    __syncthreads();
    for (int off = 1; off < 512; off <<= 1) {
        int u = (t >= off) ? s[t - off] : 0;
        __syncthreads();
        s[t] += u;
        __syncthreads();
    }
    if (t < nb) bsum[t] = s[t] - v;  // exclusive
}
__global__ void k_row_ptr(const int* __restrict__ deg, const int* __restrict__ bsum,
                          int* __restrict__ row_ptr) {
    __shared__ int s[256];
    int t = threadIdx.x;
    int i = blockIdx.x * 256 + t;
    int v = (i < N_NODES) ? deg[i] : 0;
    s[t] = v;
    __syncthreads();
    for (int off = 1; off < 256; off <<= 1) {
        int u = (t >= off) ? s[t - off] : 0;
        __syncthreads();
        s[t] += u;
        __syncthreads();
    }
    if (i < N_NODES) row_ptr[i] = bsum[blockIdx.x] + s[t] - v;  // exclusive
    if (blockIdx.x == 0 && t == 0) row_ptr[N_NODES] = N_EDGES;
}
__global__ void k_scatter(const int* __restrict__ src, const int* __restrict__ dst,
                          const int* __restrict__ row_ptr, int* __restrict__ cursor,
                          int* __restrict__ col) {
    int e = blockIdx.x * 256 + threadIdx.x;
    if (e < N_EDGES) {
        int d = dst[e];
        int p = atomicAdd(&cursor[d], 1);
        col[row_ptr[d] + p] = src[e];
    }
}

// ================= all weight transposes in one kernel =================
// wt[which][n][k] = W_which[row_off+k][n], 5 matrices of 256x256
__global__ void k_transpose_all(const float* __restrict__ W1, const float* __restrict__ W2,
                                const float* __restrict__ W3, const float* __restrict__ fc1w,
                                bf16* __restrict__ wt) {
    int which = blockIdx.x >> 8;  // 0..4
    int idx = ((blockIdx.x & 255) << 8) + threadIdx.x;
    int n = idx >> 8, k = idx & 255;
    const float* W; int ro = 0;
    switch (which) {
        case 0: W = W1; break;
        case 1: W = W2; break;
        case 2: W = W3; break;
        case 3: W = fc1w; break;
        default: W = fc1w; ro = 256; break;
    }
    wt[(size_t)which * 65536 + (size_t)n * 256 + k] =
        __float2bfloat16(W[(size_t)(ro + k) * 256 + n]);
}

// ================= casts =================
__global__ void k_cast_bf16_v4(const float* __restrict__ x, unsigned short* __restrict__ y) {
    int i = blockIdx.x * 256 + threadIdx.x;  // over NF/4
    float4 v = ((const float4*)x)[i];
    ushort4 o;
    o.x = f2bf(v.x); o.y = f2bf(v.y); o.z = f2bf(v.z); o.w = f2bf(v.w);
    ((ushort4*)y)[i] = o;
}
// in-place BN apply + relu on bf16 buffer
__global__ void k_bn_relu_bf16(unsigned short* __restrict__ x, const float* __restrict__ scale,
                               const float* __restrict__ shift) {
    int i = blockIdx.x * 256 + threadIdx.x;  // over NF/4
    ushort4 m = ((ushort4*)x)[i];
    int c = (i & 63) * 4;
    float4 sc = *(const float4*)(scale + c);
    float4 sh = *(const float4*)(shift + c);
    ushort4 o;
    o.x = f2bf(fmaxf(bf2f(m.x) * sc.x + sh.x, 0.f));
    o.y = f2bf(fmaxf(bf2f(m.y) * sc.y + sh.y, 0.f));
    o.z = f2bf(fmaxf(bf2f(m.z) * sc.z + sh.z, 0.f));
    o.w = f2bf(fmaxf(bf2f(m.w) * sc.w + sh.w, 0.f));
    ((ushort4*)x)[i] = o;
}

// ================= bf16 MFMA GEMM: C[M x N] = A[M x 256] @ Bt[N x 256]^T =================
// 128x128 tile, BK=64, 4 waves (2x2), each wave 64x64 via 4x4 of 16x16x32 MFMA.
// ldc = C row stride (N). gridDim.x = N/128.
template <typename OutT>
__global__ __launch_bounds__(256) void k_gemm_mfma(const bf16* __restrict__ A,
                                                   const bf16* __restrict__ Bt,
                                                   OutT* __restrict__ C, int M, int ldc) {
    __shared__ bf16 As[128 * 64];
    __shared__ bf16 Bs[128 * 64];
    const int tid = threadIdx.x;
    const int lane = tid & 63;
    const int w = tid >> 6;
    const int wr = w >> 1, wc = w & 1;
    const int lr = lane & 15, quad = lane >> 4;
    const int row0 = blockIdx.y * 128;
    const int col0 = blockIdx.x * 128;

    f32x4_t acc[4][4] = {};

    for (int k0 = 0; k0 < 256; k0 += 64) {
#pragma unroll
        for (int i = 0; i < 4; ++i) {
            int j = i * 256 + tid;
            int r = j >> 3, c = j & 7;
            int gk = ((c ^ (r & 7)) << 3);
            int gr = row0 + r; gr = gr < M ? gr : M - 1;
            async_copy16(A + (size_t)gr * 256 + k0 + gk, (void*)(As + j * 8));
            async_copy16(Bt + (size_t)(col0 + r) * 256 + k0 + gk, (void*)(Bs + j * 8));
        }
        __syncthreads();
#pragma unroll
        for (int ks = 0; ks < 2; ++ks) {
            bf16x8_t af[4], bfr[4];
#pragma unroll
            for (int mi = 0; mi < 4; ++mi) {
                int m = wr * 64 + mi * 16 + lr;
                int c = (ks * 4 + quad) ^ (m & 7);
                af[mi] = *(const bf16x8_t*)(As + m * 64 + c * 8);
            }
#pragma unroll
            for (int ni = 0; ni < 4; ++ni) {
                int n = wc * 64 + ni * 16 + lr;
                int c = (ks * 4 + quad) ^ (n & 7);
                bfr[ni] = *(const bf16x8_t*)(Bs + n * 64 + c * 8);
            }
#pragma unroll
            for (int mi = 0; mi < 4; ++mi)
#pragma unroll
                for (int ni = 0; ni < 4; ++ni)
                    acc[mi][ni] = __builtin_amdgcn_mfma_f32_16x16x32_bf16(
                        af[mi], bfr[ni], acc[mi][ni], 0, 0, 0);
        }
        __syncthreads();
    }
    // epilogue: C/D layout col=lane&15, row=quad*4+reg
#pragma unroll
    for (int mi = 0; mi < 4; ++mi) {
#pragma unroll
        for (int r = 0; r < 4; ++r) {
            int row = row0 + wr * 64 + mi * 16 + quad * 4 + r;
            if (row < M) {
#pragma unroll
                for (int ni = 0; ni < 4; ++ni) {
                    int colg = col0 + wc * 64 + ni * 16 + lr;
                    store_val(C + (size_t)row * ldc + colg, acc[mi][ni][r]);
                }
            }
        }
    }
}

// ================= CSR aggregation (bf16 xw in, bf16 out, no atomics) =================
__global__ void k_agg_csr(const unsigned short* __restrict__ xw, const float* __restrict__ dinv,
                          const int* __restrict__ row_ptr, const int* __restrict__ col,
                          const float* __restrict__ bias, bf16* __restrict__ out) {
    int wave = threadIdx.x >> 6, lane = threadIdx.x & 63;
    int node = blockIdx.x * 4 + wave;
    if (node >= N_NODES) return;
    int beg = row_ptr[node], end = row_ptr[node + 1];
    float dv = dinv[node];
    const ushort4* xwv = (const ushort4*)xw;
    ushort4 xr = xwv[(size_t)node * 64 + lane];
    float s2 = dv * dv;
    float4 acc;
    acc.x = s2 * bf2f(xr.x); acc.y = s2 * bf2f(xr.y);
    acc.z = s2 * bf2f(xr.z); acc.w = s2 * bf2f(xr.w);
    for (int i = beg; i < end; ++i) {
        int s = col[i];
        float wgt = dv * dinv[s];
        ushort4 m = xwv[(size_t)s * 64 + lane];
        acc.x += wgt * bf2f(m.x); acc.y += wgt * bf2f(m.y);
        acc.z += wgt * bf2f(m.z); acc.w += wgt * bf2f(m.w);
    }
    float4 bv = ((const float4*)bias)[lane];
    acc.x += bv.x; acc.y += bv.y; acc.z += bv.z; acc.w += bv.w;
    store4(out + (size_t)node * CH + lane * 4, acc);
}

// ================= batch norm stats: bf16 in, per-block partials (NO atomics) ==========
// part[b][c] = sum over block b's 64 rows (c<256: sum; c>=256: sumsq)
__global__ __launch_bounds__(256) void k_bn_stats(const unsigned short* __restrict__ x,
                                                  float* __restrict__ part) {
    __shared__ float sred[4][64][4];
    __shared__ float qred[4][64][4];
    int t = threadIdx.x;
    int cg = t & 63, rg = t >> 6;  // 64 channel-groups x 4 row-groups
    int r0 = blockIdx.x * 64;
    float s0 = 0, s1 = 0, s2 = 0, s3 = 0, q0 = 0, q1 = 0, q2 = 0, q3 = 0;
#pragma unroll
    for (int i = 0; i < 16; ++i) {
        int r = r0 + rg + 4 * i;
        if (r < N_NODES) {
            ushort4 m = ((const ushort4*)(x + (size_t)r * 256))[cg];
            float v0 = bf2f(m.x), v1 = bf2f(m.y), v2 = bf2f(m.z), v3 = bf2f(m.w);
            s0 += v0; s1 += v1; s2 += v2; s3 += v3;
            q0 += v0 * v0; q1 += v1 * v1; q2 += v2 * v2; q3 += v3 * v3;
        }
    }
    sred[rg][cg][0] = s0; sred[rg][cg][1] = s1; sred[rg][cg][2] = s2; sred[rg][cg][3] = s3;
    qred[rg][cg][0] = q0; qred[rg][cg][1] = q1; qred[rg][cg][2] = q2; qred[rg][cg][3] = q3;
    __syncthreads();
    if (rg == 0) {
        float4 sv, qv;
        sv.x = s0; sv.y = s1; sv.z = s2; sv.w = s3;
        qv.x = q0; qv.y = q1; qv.z = q2; qv.w = q3;
#pragma unroll
        for (int g = 1; g < 4; ++g) {
            sv.x += sred[g][cg][0]; sv.y += sred[g][cg][1];
            sv.z += sred[g][cg][2]; sv.w += sred[g][cg][3];
            qv.x += qred[g][cg][0]; qv.y += qred[g][cg][1];
            qv.z += qred[g][cg][2]; qv.w += qred[g][cg][3];
        }
        float* p = part + (size_t)blockIdx.x * 512;
        *(float4*)(p + cg * 4) = sv;
        *(float4*)(p + 256 + cg * 4) = qv;
    }
}
// one wave per channel: lanes stride over BN_BLOCKS partials, shuffle-reduce, compute scale/shift
__global__ __launch_bounds__(256) void k_bn_finalize(const float* __restrict__ part,
                                                     const float* __restrict__ g,
                                                     const float* __restrict__ be,
                                                     float* __restrict__ scale,
                                                     float* __restrict__ shift) {
    int wave = threadIdx.x >> 6, lane = threadIdx.x & 63;
    int c = blockIdx.x * 4 + wave;  // 0..255
    float s = 0.f, q = 0.f;
    for (int j = lane; j < BN_BLOCKS; j += 64) {
        s += part[(size_t)j * 512 + c];
        q += part[(size_t)j * 512 + 256 + c];
    }
#pragma unroll
    for (int off = 32; off > 0; off >>= 1) {
        s += __shfl_down(s, off, 64);
        q += __shfl_down(q, off, 64);
    }
    if (lane == 0) {
        float mu = s * (1.0f / N_NODES);
        float var = q * (1.0f / N_NODES) - mu * mu;
        float sc = g[c] * rsqrtf(var + EPS);
        scale[c] = sc;
        shift[c] = be[c] - mu * sc;
    }
}

// ================= edge scoring: 2 edges/wave, 32 lanes each, 8 ch/lane =================
// uv layout: [node][512] bf16, u = cols 0..255, v = cols 256..511
__global__ __launch_bounds__(256) void k_edge_score(
        const unsigned short* __restrict__ uv,
        const int* __restrict__ src, const int* __restrict__ dst,
        const int* __restrict__ neg, const float* __restrict__ fc1_b,
        const float* __restrict__ fc2_w, const float* __restrict__ fc2_b,
        float* __restrict__ out) {
    int wave = threadIdx.x >> 6, lane = threadIdx.x & 63;
    int half = lane >> 5, l = lane & 31;
    int e = blockIdx.x * 8 + wave * 2 + half;
    if (e >= N_EDGES) return;
    int s = src[e], d = dst[e], g = neg[e];
    uint4 uu = ((const uint4*)(uv + (size_t)s * 512))[l];
    uint4 vp = ((const uint4*)(uv + (size_t)d * 512 + 256))[l];
    uint4 vn = ((const uint4*)(uv + (size_t)g * 512 + 256))[l];
    float4 b0 = ((const float4*)fc1_b)[l * 2];
    float4 b1 = ((const float4*)fc1_b)[l * 2 + 1];
    float4 w0 = ((const float4*)fc2_w)[l * 2];
    float4 w1 = ((const float4*)fc2_w)[l * 2 + 1];

    float t0 = bflo(uu.x) + b0.x, t1 = bfhi(uu.x) + b0.y;
    float t2 = bflo(uu.y) + b0.z, t3 = bfhi(uu.y) + b0.w;
    float t4 = bflo(uu.z) + b1.x, t5 = bfhi(uu.z) + b1.y;
    float t6 = bflo(uu.w) + b1.z, t7 = bfhi(uu.w) + b1.w;

    float accp = fmaxf(t0 + bflo(vp.x), 0.f) * w0.x + fmaxf(t1 + bfhi(vp.x), 0.f) * w0.y +
                 fmaxf(t2 + bflo(vp.y), 0.f) * w0.z + fmaxf(t3 + bfhi(vp.y), 0.f) * w0.w +
                 fmaxf(t4 + bflo(vp.z), 0.f) * w1.x + fmaxf(t5 + bfhi(vp.z), 0.f) * w1.y +
                 fmaxf(t6 + bflo(vp.w), 0.f) * w1.z + fmaxf(t7 + bfhi(vp.w), 0.f) * w1.w;
    float accn = fmaxf(t0 + bflo(vn.x), 0.f) * w0.x + fmaxf(t1 + bfhi(vn.x), 0.f) * w0.y +
                 fmaxf(t2 + bflo(vn.y), 0.f) * w0.z + fmaxf(t3 + bfhi(vn.y), 0.f) * w0.w +
                 fmaxf(t4 + bflo(vn.z), 0.f) * w1.x + fmaxf(t5 + bfhi(vn.z), 0.f) * w1.y +
                 fmaxf(t6 + bflo(vn.w), 0.f) * w1.z + fmaxf(t7 + bfhi(vn.w), 0.f) * w1.w;
#pragma unroll
    for (int off = 16; off > 0; off >>= 1) {
        accp += __shfl_down(accp, off, 64);
        accn += __shfl_down(accn, off, 64);
    }
    if (l == 0) {
        float bb = fc2_b[0];
        out[e] = 1.0f / (1.0f + expf(-(accp + bb)));
        out[N_EDGES + e] = 1.0f / (1.0f + expf(-(accn + bb)));
    }
}

extern "C" void kernel_launch(void* const* d_in, const int* in_sizes, int n_in,
                              void* d_out, int out_size, void* d_ws, size_t ws_size,
                              hipStream_t stream) {
    const float* node_feat = (const float*)d_in[0];
    const int* src = (const int*)d_in[1];
    const int* dst = (const int*)d_in[2];
    const int* neg = (const int*)d_in[3];
    const float* W1 = (const float*)d_in[4];  const float* b1 = (const float*)d_in[5];
    const float* W2 = (const float*)d_in[6];  const float* b2 = (const float*)d_in[7];
    const float* W3 = (const float*)d_in[8];  const float* b3 = (const float*)d_in[9];
    const float* g1 = (const float*)d_in[10]; const float* be1 = (const float*)d_in[11];
    const float* g2 = (const float*)d_in[12]; const float* be2 = (const float*)d_in[13];
    const float* fc1_w = (const float*)d_in[14]; const float* fc1_b = (const float*)d_in[15];
    const float* fc2_w = (const float*)d_in[16]; const float* fc2_b = (const float*)d_in[17];
    float* out = (float*)d_out;

    // ---- workspace layout (~211 MB total, all-bf16 activations) ----
    const size_t NF = (size_t)N_NODES * CH;  // 25,600,000
    bf16* UV = (bf16*)d_ws;                  // [node][512] u|v (2*NF)
    bf16* Xbf = UV + 2 * NF;                 // bf16 activations / agg out / z (NF)
    bf16* XwBf = Xbf + NF;                   // bf16 GEMM output xw (NF)
    bf16* wt = XwBf + NF;                    // 5 * 65536 (wt1,wt2,wt3,wtu,wtv)
    float* dinv = (float*)(wt + 5 * 65536);
    float* bnpart = dinv + N_NODES;          // BN_BLOCKS * 512 (3.2 MB)
    float* scale = bnpart + (size_t)BN_BLOCKS * 512;
    float* shift = scale + CH;
    int* ideg = (int*)(shift + CH);          // N (cursor follows: zeroed together)
    int* cursor = ideg + N_NODES;
    int* row_ptr = cursor + N_NODES;
    int* col = row_ptr + N_NODES + 1;
    int* bsum = col + N_EDGES;               // 512
    (void)ws_size;

    dim3 gemmGrid(2, (N_NODES + 127) / 128);   // 2 x 782
    dim3 uvGrid(4, (N_NODES + 127) / 128);     // 4 x 782 (N=512)
    int nodeBlocks = (N_NODES + 255) / 256;    // 391
    int edgeBlocks = (N_EDGES + 255) / 256;
    int aggBlocks = (N_NODES + 3) / 4;
    int v4Blocks = (int)(NF / 4 / 256);        // 25000
    int scoreBlocks = (N_EDGES + 7) / 8;       // 37500

    // ---- CSR build + dinv ----
    k_zero_int<<<(2 * N_NODES + 255) / 256, 256, 0, stream>>>(ideg, 2 * N_NODES);
    k_count_deg<<<edgeBlocks, 256, 0, stream>>>(dst, ideg);
    k_dinv_from_deg<<<nodeBlocks, 256, 0, stream>>>(ideg, dinv);
    k_block_sums<<<nodeBlocks, 256, 0, stream>>>(ideg, bsum);
    k_scan_bsums<<<1, 512, 0, stream>>>(bsum, nodeBlocks);
    k_row_ptr<<<nodeBlocks, 256, 0, stream>>>(ideg, bsum, row_ptr);
    k_scatter<<<edgeBlocks, 256, 0, stream>>>(src, dst, row_ptr, cursor, col);

    // ---- all weight transposes ----
    k_transpose_all<<<1280, 256, 0, stream>>>(W1, W2, W3, fc1_w, wt);

    // ---- layer 1 ----
    k_cast_bf16_v4<<<v4Blocks, 256, 0, stream>>>(node_feat, (unsigned short*)Xbf);
    k_gemm_mfma<bf16><<<gemmGrid, 256, 0, stream>>>(Xbf, wt, XwBf, N_NODES, 256);
    k_agg_csr<<<aggBlocks, 256, 0, stream>>>((unsigned short*)XwBf, dinv, row_ptr, col, b1, Xbf);
    k_bn_stats<<<BN_BLOCKS, 256, 0, stream>>>((unsigned short*)Xbf, bnpart);
    k_bn_finalize<<<64, 256, 0, stream>>>(bnpart, g1, be1, scale, shift);
    k_bn_relu_bf16<<<v4Blocks, 256, 0, stream>>>((unsigned short*)Xbf, scale, shift);

    // ---- layer 2 ----
    k_gemm_mfma<bf16><<<gemmGrid, 256, 0, stream>>>(Xbf, wt + 65536, XwBf, N_NODES, 256);
    k_agg_csr<<<aggBlocks, 256, 0, stream>>>((unsigned short*)XwBf, dinv, row_ptr, col, b2, Xbf);
    k_bn_stats<<<BN_BLOCKS, 256, 0, stream>>>((unsigned short*)Xbf, bnpart);
    k_bn_finalize<<<64, 256, 0, stream>>>(bnpart, g2, be2, scale, shift);
    k_bn_relu_bf16<<<v4Blocks, 256, 0, stream>>>((unsigned short*)Xbf, scale, shift);

    // ---- layer 3: agg writes z (bf16) into Xbf ----
    k_gemm_mfma<bf16><<<gemmGrid, 256, 0, stream>>>(Xbf, wt + 2 * 65536, XwBf, N_NODES, 256);
    k_agg_csr<<<aggBlocks, 256, 0, stream>>>((unsigned short*)XwBf, dinv, row_ptr, col, b3, Xbf);

    // ---- link predictor: UV = z @ [wtu|wtv]^T (single N=512 GEMM) ----
    k_gemm_mfma<bf16><<<uvGrid, 256, 0, stream>>>(Xbf, wt + 3 * 65536, UV, N_NODES, 512);
    k_edge_score<<<scoreBlocks, 256, 0, stream>>>((unsigned short*)UV, src, dst, neg,
                                                  fc1_b, fc2_w, fc2_b, out);
}